// Round 1
// baseline (331.965 us; speedup 1.0000x reference)
//
#include <hip/hip_runtime.h>
#include <hip/hip_bf16.h>

#define DEV static __device__ __forceinline__

constexpr int F1 = 128;   // input features
constexpr int H1 = 8;     // heads layer1
constexpr int C  = 64;    // channels per head
constexpr int B  = 64;    // graphs
constexpr int K  = 10;    // classes
constexpr float NEG = 0.2f;

typedef __attribute__((ext_vector_type(8))) short short8;
typedef __attribute__((ext_vector_type(4))) float floatx4;

DEV float b2f(__hip_bfloat16 x) { return __bfloat162float(x); }
DEV float elu1(float v) { return v > 0.f ? v : (__expf(v) - 1.f); }
DEV unsigned short f2bbits(float f) {
  __hip_bfloat16 b = __float2bfloat16(f);
  return *(unsigned short*)&b;
}
DEV float blo(unsigned u) { return __uint_as_float(u << 16); }
DEV float bhi(unsigned u) { return __uint_as_float(u & 0xffff0000u); }
DEV float bu(unsigned short u) { return __uint_as_float(((unsigned)u) << 16); }
DEV unsigned pack2(float lo, float hi) {
  return (unsigned)f2bbits(lo) | ((unsigned)f2bbits(hi) << 16);
}

// out1 PERMUTED layout: position p = hp*128 + l16*8 + nt  <->  natural channel
// c = hp*128 + nt*16 + l16  (hp<4, l16<16, nt<8). Dot products over the
// contraction dim are permutation-invariant; W2frag k-rows and b1 are
// permuted to match.

// Self-detection: thread 0 samples 128 even-index bf16 reinterps of x.
DEV int detect_dev(const void* xraw, int* lds) {
  if (threadIdx.x == 0) {
    const __hip_bfloat16* xb = (const __hip_bfloat16*)xraw;
    int bad = 0;
    for (int i = 0; i < 128; ++i) {
      float v = b2f(xb[2 * i]);
      if (!(fabsf(v) < 1e4f)) bad++;
    }
    *lds = (bad < 13) ? 1 : 0;     // 1 = bf16, 0 = f32
  }
  __syncthreads();
  return *lds;
}

#define CVT(p, i) (isbf ? b2f(((const __hip_bfloat16*)(p))[i]) : ((const float*)(p))[i])

// ---------- fused prep ----------
__global__ void fused_prep_kernel(const void* x_raw, const void* w1raw,
                                  const void* as1r, const void* ad1r, const void* b1r,
                                  const void* w2raw,
                                  const void* as2r, const void* ad2r, const void* b2r,
                                  const void* l1wr, const void* l1br,
                                  const void* l2wr, const void* l2br,
                                  unsigned short* __restrict__ xbf,
                                  unsigned short* __restrict__ w1frag,
                                  unsigned short* __restrict__ w2frag,
                                  float* __restrict__ wts,
                                  int* __restrict__ deg,
                                  float* __restrict__ pooled,
                                  int nX, int N) {
  __shared__ int fl;
  int isbf = detect_dev(x_raw, &fl);
  int gid = blockIdx.x * 256 + threadIdx.x;
  int stride = gridDim.x * 256;

  if (isbf) {
    const unsigned short* src = (const unsigned short*)x_raw;
    for (int i = gid; i < nX; i += stride) xbf[i] = src[i];
  } else {
    const float* src = (const float*)x_raw;
    for (int i = gid; i < nX; i += stride) xbf[i] = f2bbits(src[i]);
  }
  for (int i = gid; i < 512;  i += stride) wts[0    + i] = CVT(as1r, i);
  for (int i = gid; i < 512;  i += stride) wts[512  + i] = CVT(ad1r, i);
  // b1 stored PERMUTED: wts[1024 + p] = b1[c_nat(p)]
  for (int i = gid; i < 512;  i += stride) {
    int hp = i >> 7, l16 = (i >> 3) & 15, nt = i & 7;
    int c = hp * 128 + nt * 16 + l16;
    wts[1024 + i] = CVT(b1r, c);
  }
  for (int i = gid; i < 64;   i += stride) wts[1536 + i] = CVT(as2r, i);
  for (int i = gid; i < 64;   i += stride) wts[1600 + i] = CVT(ad2r, i);
  for (int i = gid; i < 64;   i += stride) wts[1664 + i] = CVT(b2r, i);
  for (int i = gid; i < 4096; i += stride) wts[1728 + i] = CVT(l1wr, i);
  for (int i = gid; i < 64;   i += stride) wts[5824 + i] = CVT(l1br, i);
  for (int i = gid; i < 640;  i += stride) wts[5888 + i] = CVT(l2wr, i);
  for (int i = gid; i < 10;   i += stride) wts[6528 + i] = CVT(l2br, i);
  for (int t = gid; t < 8192; t += stride) {
    int lane = t & 63, ks = (t >> 6) & 3, nt = t >> 8;
    for (int j = 0; j < 8; ++j) {
      int k = ks * 32 + (lane >> 4) * 8 + j;
      int n = nt * 16 + (lane & 15);
      w1frag[t * 8 + j] = f2bbits(CVT(w1raw, k * 512 + n));
    }
  }
  // W2frag with PERMUTED k: k index in fragment = position p; fetch W2[c_nat(p)]
  for (int t = gid; t < 4096; t += stride) {
    int lane = t & 63, nt = (t >> 6) & 3, ks = t >> 8;
    for (int j = 0; j < 8; ++j) {
      int p = ks * 32 + (lane >> 4) * 8 + j;          // permuted position
      int hp = p >> 7, pl16 = (p >> 3) & 15, pnt = p & 7;
      int k = hp * 128 + pnt * 16 + pl16;             // natural channel
      int n = nt * 16 + (lane & 15);
      w2frag[t * 8 + j] = f2bbits(CVT(w2raw, k * 64 + n));
    }
  }
  for (int i = gid; i < N; i += stride) deg[i] = 0;
  for (int i = gid; i < B * C; i += stride) pooled[i] = 0.f;
}

// ---------- degree count ----------
__global__ void deg_count_kernel(const int* __restrict__ ei, int E, int Etot,
                                 int* __restrict__ deg) {
  int e = blockIdx.x * blockDim.x + threadIdx.x;
  if (e >= Etot) return;
  int d = (e < E) ? ei[E + e] : e - E;
  atomicAdd(&deg[d], 1);
}

// ---------- CSR scans ----------
__global__ void scan_block_kernel(const int* __restrict__ deg,
                                  int* __restrict__ local,
                                  int* __restrict__ bsum, int N) {
  __shared__ int tmp[256];
  int t = threadIdx.x;
  int i = blockIdx.x * 256 + t;
  int v = (i < N) ? deg[i] : 0;
  tmp[t] = v;
  __syncthreads();
  for (int off = 1; off < 256; off <<= 1) {
    int u = (t >= off) ? tmp[t - off] : 0;
    __syncthreads();
    tmp[t] += u;
    __syncthreads();
  }
  if (i < N) local[i] = tmp[t] - v;
  if (t == 255) bsum[blockIdx.x] = tmp[255];
}

__global__ void scan_finish_kernel(const int* __restrict__ local,
                                   const int* __restrict__ bsum, int nb,
                                   int* __restrict__ rowptr,
                                   int* __restrict__ cursor, int N, int Etot) {
  __shared__ int tmp[256];
  __shared__ int offs;
  int t = threadIdx.x;
  int v0 = (t < nb) ? bsum[t] : 0;
  tmp[t] = v0;
  __syncthreads();
  for (int off = 1; off < 256; off <<= 1) {
    int u = (t >= off) ? tmp[t - off] : 0;
    __syncthreads();
    tmp[t] += u;
    __syncthreads();
  }
  if (t == (int)blockIdx.x) offs = tmp[t] - v0;
  __syncthreads();
  int i = blockIdx.x * 256 + t;
  if (i < N) {
    int r = local[i] + offs;
    rowptr[i] = r;
    cursor[i] = r;
  }
  if (i == 0) rowptr[N] = Etot;
}

// ---------- layer-1 MFMA GEMM: attention scalars only (no h1 store) ----------
__global__ __launch_bounds__(256) void gemm1_att_kernel(
    const unsigned short* __restrict__ xbf,     // N x 128 bf16
    const unsigned short* __restrict__ W1frag,  // [32][4][64][8] bf16
    const float* __restrict__ att_src,          // 512
    const float* __restrict__ att_dst,
    float* __restrict__ a_s, float* __restrict__ a_d,   // N x 8
    int N) {
  __shared__ __align__(16) unsigned short Xls[64 * 136];
  int t = threadIdx.x;
  int w = t >> 6, lane = t & 63;
  int quad = lane >> 4, l16 = lane & 15;
  int blkbase = blockIdx.x * 64;
  int rowbase = blkbase + w * 16;

  for (int idx = t; idx < 1024; idx += 256) {
    int row = idx >> 4, c = idx & 15;
    int rg = blkbase + row; if (rg >= N) rg = N - 1;
    *(uint4*)&Xls[row * 136 + c * 8] =
        *(const uint4*)(xbf + (size_t)rg * 128 + c * 8);
  }
  __syncthreads();

  short8 afr[4];
  {
    int rl = w * 16 + l16;
#pragma unroll
    for (int ks = 0; ks < 4; ++ks)
      afr[ks] = *(const short8*)&Xls[rl * 136 + ks * 32 + quad * 8];
  }

  for (int hp = 0; hp < 4; ++hp) {
    floatx4 acc[8] = {};
    const unsigned short* Bp = W1frag + (size_t)hp * 16384;
#pragma unroll
    for (int nt = 0; nt < 8; ++nt)
#pragma unroll
      for (int ks = 0; ks < 4; ++ks) {
        short8 b = *(const short8*)&Bp[((nt * 4 + ks) * 64 + lane) * 8];
        acc[nt] = __builtin_amdgcn_mfma_f32_16x16x32_bf16(afr[ks], b, acc[nt], 0, 0, 0);
      }

    // attention coefs (natural channel indexing, from registers)
    float asw[8], adw[8];
#pragma unroll
    for (int nt = 0; nt < 8; ++nt) {
      asw[nt] = att_src[hp * 128 + nt * 16 + l16];
      adw[nt] = att_dst[hp * 128 + nt * 16 + l16];
    }
    float ps[2][4] = {}, pd[2][4] = {};
#pragma unroll
    for (int nt = 0; nt < 8; ++nt) {
      int hl = nt >> 2;
#pragma unroll
      for (int r = 0; r < 4; ++r) {
        ps[hl][r] += acc[nt][r] * asw[nt];
        pd[hl][r] += acc[nt][r] * adw[nt];
      }
    }
#pragma unroll
    for (int hl = 0; hl < 2; ++hl)
#pragma unroll
      for (int r = 0; r < 4; ++r) {
        float p = ps[hl][r], q = pd[hl][r];
#pragma unroll
        for (int off = 1; off < 16; off <<= 1) {
          p += __shfl_xor(p, off);
          q += __shfl_xor(q, off);
        }
        int row = rowbase + quad * 4 + r;
        if (l16 == 0 && row < N) {
          a_s[(size_t)row * 8 + hp * 2 + hl] = p;
          a_d[(size_t)row * 8 + hp * 2 + hl] = q;
        }
      }
  }
}

// ---------- CSR fill + per-edge softmax weights (f32, CSR slot order) ----------
__global__ void fill_weight_kernel(const int* __restrict__ ei, int E, int Etot,
                                   const float* __restrict__ a_s,
                                   const float* __restrict__ a_d,
                                   int* __restrict__ cursor,
                                   int* __restrict__ col,
                                   float* __restrict__ wedge) {
  int e = blockIdx.x * 256 + threadIdx.x;
  if (e >= Etot) return;
  int s, d;
  if (e < E) { s = ei[e]; d = ei[E + e]; } else { s = d = e - E; }
  int pos = atomicAdd(&cursor[d], 1);
  col[pos] = s;
  float4 s0 = *(const float4*)(a_s + (size_t)s * 8);
  float4 s1 = *(const float4*)(a_s + (size_t)s * 8 + 4);
  float4 d0 = *(const float4*)(a_d + (size_t)d * 8);
  float4 d1 = *(const float4*)(a_d + (size_t)d * 8 + 4);
  float4 w0, w1;
  float v;
  v = s0.x + d0.x; v = v > 0.f ? v : NEG * v; w0.x = __expf(v);
  v = s0.y + d0.y; v = v > 0.f ? v : NEG * v; w0.y = __expf(v);
  v = s0.z + d0.z; v = v > 0.f ? v : NEG * v; w0.z = __expf(v);
  v = s0.w + d0.w; v = v > 0.f ? v : NEG * v; w0.w = __expf(v);
  v = s1.x + d1.x; v = v > 0.f ? v : NEG * v; w1.x = __expf(v);
  v = s1.y + d1.y; v = v > 0.f ? v : NEG * v; w1.y = __expf(v);
  v = s1.z + d1.z; v = v > 0.f ? v : NEG * v; w1.z = __expf(v);
  v = s1.w + d1.w; v = v > 0.f ? v : NEG * v; w1.w = __expf(v);
  *(float4*)(wedge + (size_t)pos * 8)     = w0;
  *(float4*)(wedge + (size_t)pos * 8 + 4) = w1;
}

// ---------- fused x-space aggregation + W1 MFMA + bias/ELU -> out1 ----------
// out1[d,h,:] = (sum_s w[s,d,h] * x[s]) / denom @ W1[:,h] + b1, then ELU.
// Block = 16 dests, 4 waves; wave aggregates 4 dests (lane = feature dword),
// then all waves do the [16x128]@[128x512] per-head GEMM from LDS.
__global__ __launch_bounds__(256) void aggx_gemm1_kernel(
    const unsigned short* __restrict__ xbf,     // N x 128 bf16
    const unsigned short* __restrict__ W1frag,  // [32][4][64][8] bf16
    const int* __restrict__ rowptr,
    const int* __restrict__ col,
    const float* __restrict__ wedge,            // Etot x 8 f32 (CSR order)
    const float* __restrict__ bias_perm,        // 512, PERMUTED
    unsigned short* __restrict__ out1,          // N x 512 bf16 (PERMUTED)
    int N) {
  // per-head aggregate tiles: [8 heads][16 dests][128+8pad] bf16 = 34 KB
  __shared__ __align__(16) unsigned short Agg[8 * 16 * 136];
  int t = threadIdx.x, w = t >> 6, lane = t & 63;
  int dbase = blockIdx.x * 16;
  const unsigned* xd = (const unsigned*)xbf;
  unsigned* AggU = (unsigned*)Agg;

  // ---- phase 1: aggregate weighted x rows ----
  for (int j = 0; j < 4; ++j) {
    int dloc = w * 4 + j;
    int d = dbase + dloc;
    int dd = d < N ? d : N - 1;
    int beg = rowptr[dd], end = rowptr[dd + 1];
    float acc[16] = {};     // [h][2 feats]
    float dn[8] = {};
#pragma unroll 4
    for (int i = beg; i < end; ++i) {
      int iu = __builtin_amdgcn_readfirstlane(i);
      int s = col[iu];                            // wave-uniform -> s_load
      unsigned xv = xd[(size_t)s * 64 + lane];    // 256B coalesced gather
      float4 wa = *(const float4*)(wedge + (size_t)iu * 8);      // scalar
      float4 wb = *(const float4*)(wedge + (size_t)iu * 8 + 4);
      float x0 = blo(xv), x1 = bhi(xv);
      acc[0]  += wa.x * x0; acc[1]  += wa.x * x1; dn[0] += wa.x;
      acc[2]  += wa.y * x0; acc[3]  += wa.y * x1; dn[1] += wa.y;
      acc[4]  += wa.z * x0; acc[5]  += wa.z * x1; dn[2] += wa.z;
      acc[6]  += wa.w * x0; acc[7]  += wa.w * x1; dn[3] += wa.w;
      acc[8]  += wb.x * x0; acc[9]  += wb.x * x1; dn[4] += wb.x;
      acc[10] += wb.y * x0; acc[11] += wb.y * x1; dn[5] += wb.y;
      acc[12] += wb.z * x0; acc[13] += wb.z * x1; dn[6] += wb.z;
      acc[14] += wb.w * x0; acc[15] += wb.w * x1; dn[7] += wb.w;
    }
#pragma unroll
    for (int h = 0; h < 8; ++h) {
      float inv = 1.f / (dn[h] + 1e-16f);
      AggU[(h * 16 + dloc) * 68 + lane] =
          pack2(acc[2 * h] * inv, acc[2 * h + 1] * inv);
    }
  }
  __syncthreads();

  // ---- phase 2: per-head GEMM from LDS, bias + ELU, permuted store ----
  int quad = lane >> 4, l16 = lane & 15;
  int hp = w;                                    // wave = head-pair
  short8 afr[2][4];
#pragma unroll
  for (int hh = 0; hh < 2; ++hh) {
    int h = hp * 2 + hh;
#pragma unroll
    for (int ks = 0; ks < 4; ++ks)
      afr[hh][ks] = *(const short8*)&Agg[(h * 16 + l16) * 136 + ks * 32 + quad * 8];
  }
  floatx4 acc2[8] = {};
  const unsigned short* Bp = W1frag + (size_t)hp * 16384;
#pragma unroll
  for (int nt = 0; nt < 8; ++nt) {
    int hh = nt >> 2;                            // head within pair for these cols
#pragma unroll
    for (int ks = 0; ks < 4; ++ks) {
      short8 b = *(const short8*)&Bp[((nt * 4 + ks) * 64 + lane) * 8];
      acc2[nt] = __builtin_amdgcn_mfma_f32_16x16x32_bf16(afr[hh][ks], b, acc2[nt], 0, 0, 0);
    }
  }
  float4 b0 = *(const float4*)&bias_perm[hp * 128 + l16 * 8];
  float4 b1 = *(const float4*)&bias_perm[hp * 128 + l16 * 8 + 4];
#pragma unroll
  for (int r = 0; r < 4; ++r) {
    int row = dbase + quad * 4 + r;
    if (row < N) {
      uint4 o;
      o.x = pack2(elu1(acc2[0][r] + b0.x), elu1(acc2[1][r] + b0.y));
      o.y = pack2(elu1(acc2[2][r] + b0.z), elu1(acc2[3][r] + b0.w));
      o.z = pack2(elu1(acc2[4][r] + b1.x), elu1(acc2[5][r] + b1.y));
      o.w = pack2(elu1(acc2[6][r] + b1.z), elu1(acc2[7][r] + b1.w));
      *(uint4*)&out1[(size_t)row * 512 + hp * 128 + l16 * 8] = o;
    }
  }
}

// ---------- layer 2: MFMA bf16 GEMM (k-dim permuted to match out1bf) ----------
__global__ __launch_bounds__(256) void gemm2_mfma_kernel(
    const unsigned short* __restrict__ x2bf,    // N x 512 bf16 (PERMUTED k)
    const unsigned short* __restrict__ W2frag,  // [16ks][4nt][64][8] bf16 (perm k)
    const float* __restrict__ att_src,          // 64
    const float* __restrict__ att_dst,
    unsigned short* __restrict__ h2,            // N x 64 bf16 (natural)
    float* __restrict__ a_s, float* __restrict__ a_d,  // N
    int N) {
  int t = threadIdx.x;
  int w = t >> 6, lane = t & 63;
  int quad = lane >> 4, l16 = lane & 15;
  int rowbase = blockIdx.x * 64 + w * 16;

  floatx4 acc[4] = {};
  int r0 = rowbase + l16; if (r0 >= N) r0 = N - 1;
  const unsigned short* p0 = x2bf + (size_t)r0 * 512 + quad * 8;
#pragma unroll
  for (int ks = 0; ks < 16; ++ks) {
    short8 a0 = *(const short8*)(p0 + ks * 32);
#pragma unroll
    for (int nt = 0; nt < 4; ++nt) {
      short8 b = *(const short8*)&W2frag[((ks * 4 + nt) * 64 + lane) * 8];
      acc[nt] = __builtin_amdgcn_mfma_f32_16x16x32_bf16(a0, b, acc[nt], 0, 0, 0);
    }
  }

  float asw[4], adw[4];
#pragma unroll
  for (int nt = 0; nt < 4; ++nt) {
    asw[nt] = att_src[nt * 16 + l16];
    adw[nt] = att_dst[nt * 16 + l16];
  }
  float ps[4] = {}, pd[4] = {};
#pragma unroll
  for (int nt = 0; nt < 4; ++nt)
#pragma unroll
    for (int r = 0; r < 4; ++r) {
      float v = acc[nt][r];
      int row = rowbase + quad * 4 + r;
      if (row < N) h2[(size_t)row * 64 + nt * 16 + l16] = f2bbits(v);
      ps[r] += v * asw[nt];
      pd[r] += v * adw[nt];
    }
#pragma unroll
  for (int r = 0; r < 4; ++r) {
    float p = ps[r], q = pd[r];
#pragma unroll
    for (int off = 1; off < 16; off <<= 1) {
      p += __shfl_xor(p, off);
      q += __shfl_xor(q, off);
    }
    int row = rowbase + quad * 4 + r;
    if (l16 == 0 && row < N) {
      a_s[row] = p;
      a_d[row] = q;
    }
  }
}

// H=1, quarter-wave edge grouping (h2 natural layout).
__global__ void gat_agg1_kernel(const int* __restrict__ rowptr,
                                const int* __restrict__ col,
                                const float* __restrict__ a_s,
                                const float* __restrict__ a_d,
                                const unsigned short* __restrict__ hfeat,
                                const float* __restrict__ bias,
                                unsigned short* __restrict__ out, int N) {
  int wave = threadIdx.x >> 6, lane = threadIdx.x & 63;
  int d = blockIdx.x * 4 + wave;
  if (d >= N) return;
  int beg = rowptr[d], end = rowptr[d + 1];
  int qg = lane >> 4, l16 = lane & 15;
  float adv = a_d[d];
  const uint2* hfu = (const uint2*)hfeat;
  float acc[4] = {};
  float wsum = 0.f;
#pragma unroll 2
  for (int i = beg + qg; i < end; i += 4) {
    int s = col[i];
    float v = a_s[s] + adv;
    v = v > 0.f ? v : NEG * v;
    float wv = __expf(v);
    wsum += wv;
    uint2 u = hfu[(size_t)s * 16 + l16];
    acc[0] += wv * blo(u.x); acc[1] += wv * bhi(u.x);
    acc[2] += wv * blo(u.y); acc[3] += wv * bhi(u.y);
  }
#pragma unroll
  for (int off = 16; off <= 32; off <<= 1) {
#pragma unroll
    for (int j = 0; j < 4; ++j) acc[j] += __shfl_xor(acc[j], off);
    wsum += __shfl_xor(wsum, off);
  }
  float winv = 1.f / (wsum + 1e-16f);
  float4 bb = ((const float4*)bias)[l16];
  float r0 = elu1(acc[0] * winv + bb.x), r1 = elu1(acc[1] * winv + bb.y);
  float r2 = elu1(acc[2] * winv + bb.z), r3 = elu1(acc[3] * winv + bb.w);
  if (qg == 0) {
    uint2 o; o.x = pack2(r0, r1); o.y = pack2(r2, r3);
    ((uint2*)out)[(size_t)d * 16 + l16] = o;
  }
}

// ---------- pooling: 16 nodes per wave ----------
__global__ void pool_kernel(const unsigned short* __restrict__ out2,
                            const int* __restrict__ batch,
                            float* __restrict__ pooled, int N) {
  int wave = threadIdx.x >> 6, lane = threadIdx.x & 63;
  int seg = blockIdx.x * 4 + wave;
  int start = seg * 16;
  if (start >= N) return;
  int end = min(start + 16, N);
  int cur = batch[start];
  float acc = 0.f;
  for (int n = start; n < end; ++n) {
    int bn = batch[n];
    if (bn != cur) {
      unsafeAtomicAdd(&pooled[cur * 64 + lane], acc);
      acc = 0.f; cur = bn;
    }
    acc += bu(out2[(size_t)n * 64 + lane]);
  }
  unsafeAtomicAdd(&pooled[cur * 64 + lane], acc);
}

// ---------- MLP head + log_softmax: one block (one wave) per graph ----------
__global__ void head_kernel(const float* __restrict__ pooled,
                            const float* __restrict__ lin1_w,
                            const float* __restrict__ lin1_b,
                            const float* __restrict__ lin2_w,
                            const float* __restrict__ lin2_b,
                            const void* __restrict__ x_raw,
                            void* __restrict__ outv) {
  __shared__ float P[C];
  __shared__ float Zs[C];
  __shared__ float Ls[K];
  __shared__ float lse_s;
  __shared__ int fl;
  int isbf = detect_dev(x_raw, &fl);
  int g = blockIdx.x, t = threadIdx.x;   // 64 threads
  P[t] = pooled[g * C + t];
  __syncthreads();
  float acc = lin1_b[t];
  for (int k = 0; k < C; ++k) acc += P[k] * lin1_w[k * C + t];
  Zs[t] = elu1(acc);
  __syncthreads();
  if (t < K) {
    float a = lin2_b[t];
    for (int k = 0; k < C; ++k) a += Zs[k] * lin2_w[k * K + t];
    Ls[t] = a;
  }
  __syncthreads();
  if (t == 0) {
    float mx = -1e30f;
    for (int c = 0; c < K; ++c) mx = fmaxf(mx, Ls[c]);
    float s = 0.f;
    for (int c = 0; c < K; ++c) s += __expf(Ls[c] - mx);
    lse_s = mx + __logf(s);
  }
  __syncthreads();
  if (t < K) {
    float val = Ls[t] - lse_s;
    if (isbf) ((__hip_bfloat16*)outv)[g * K + t] = __float2bfloat16(val);
    else      ((float*)outv)[g * K + t] = val;
  }
}

extern "C" void kernel_launch(void* const* d_in, const int* in_sizes, int n_in,
                              void* d_out, int out_size, void* d_ws, size_t ws_size,
                              hipStream_t stream) {
  const void* x_raw = d_in[0];
  const int*  ei    = (const int*)d_in[1];
  const int*  batch = (const int*)d_in[2];

  const int N    = in_sizes[2];
  const int E    = in_sizes[1] / 2;
  const int Etot = E + N;
  const int nb   = (N + 255) / 256;

  float* ws   = (float*)d_ws;
  size_t off  = 0;

  float* wts = ws + off; off += 6544;
  float* as1w = wts + 0;
  float* ad1w = wts + 512;
  float* b1w  = wts + 1024;
  float* as2w = wts + 1536;
  float* ad2w = wts + 1600;
  float* b2w  = wts + 1664;
  float* l1w  = wts + 1728;
  float* l1b  = wts + 5824;
  float* l2w  = wts + 5888;
  float* l2b  = wts + 6528;

  unsigned short* xbf    = (unsigned short*)(ws + off); off += (size_t)N * 64;
  unsigned short* w1frag = (unsigned short*)(ws + off); off += 32768;
  unsigned short* w2frag = (unsigned short*)(ws + off); off += 16384;
  float* wedge           = ws + off;                    off += (size_t)Etot * 8;
  unsigned short* out1bf = (unsigned short*)(ws + off); off += (size_t)N * 256;
  unsigned short* h2bf   = (unsigned short*)(ws + off); off += (size_t)N * 32;
  unsigned short* out2bf = (unsigned short*)(ws + off); off += (size_t)N * 32;
  float* as1  = ws + off; off += (size_t)N * H1;
  float* ad1  = ws + off; off += (size_t)N * H1;
  float* as2  = ws + off; off += (size_t)N;
  float* ad2  = ws + off; off += (size_t)N;
  float* pooled = ws + off; off += (size_t)B * C;

  int* ibase  = (int*)(ws + off);
  int* deg    = ibase;                 ibase += N;
  int* cursor = ibase;                 ibase += N;
  int* rowptr = ibase;                 ibase += N + 1;
  int* locals = ibase;                 ibase += N;
  int* bsum   = ibase;                 ibase += 256;
  int* col    = ibase;                 ibase += Etot;

  // ---- prep ----
  fused_prep_kernel<<<1024, 256, 0, stream>>>(
      x_raw, d_in[3], d_in[4], d_in[5], d_in[6], d_in[7], d_in[8], d_in[9],
      d_in[10], d_in[11], d_in[12], d_in[13], d_in[14],
      xbf, w1frag, w2frag, wts, deg, pooled, in_sizes[0], N);

  // ---- CSR: deg + scans ----
  deg_count_kernel<<<(Etot + 255) / 256, 256, 0, stream>>>(ei, E, Etot, deg);
  scan_block_kernel<<<nb, 256, 0, stream>>>(deg, locals, bsum, N);
  scan_finish_kernel<<<nb, 256, 0, stream>>>(locals, bsum, nb, rowptr, cursor, N, Etot);

  // ---- layer-1 attention scalars (no h1 materialization) ----
  gemm1_att_kernel<<<(N + 63) / 64, 256, 0, stream>>>(xbf, w1frag, as1w, ad1w,
                                                      as1, ad1, N);

  // ---- CSR fill + per-edge softmax weights ----
  fill_weight_kernel<<<(Etot + 255) / 256, 256, 0, stream>>>(
      ei, E, Etot, as1, ad1, cursor, col, wedge);

  // ---- fused x-space aggregation + W1 GEMM -> out1 ----
  aggx_gemm1_kernel<<<(N + 15) / 16, 256, 0, stream>>>(
      xbf, w1frag, rowptr, col, wedge, b1w, out1bf, N);

  // ---- layer 2 ----
  gemm2_mfma_kernel<<<(N + 63) / 64, 256, 0, stream>>>(out1bf, w2frag, as2w, ad2w,
                                                       h2bf, as2, ad2, N);
  gat_agg1_kernel<<<(N + 3) / 4, 256, 0, stream>>>(rowptr, col, as2, ad2, h2bf, b2w, out2bf, N);

  // ---- pool + head ----
  pool_kernel<<<(N + 63) / 64, 256, 0, stream>>>(out2bf, batch, pooled, N);
  head_kernel<<<B, 64, 0, stream>>>(pooled, l1w, l1b, l2w, l2b, x_raw, (void*)d_out);
}

// Round 2
// 303.779 us; speedup vs baseline: 1.0928x; 1.0928x over previous
//
#include <hip/hip_runtime.h>
#include <hip/hip_bf16.h>

#define DEV static __device__ __forceinline__

constexpr int F1 = 128;   // input features
constexpr int H1 = 8;     // heads layer1
constexpr int C  = 64;    // channels per head
constexpr int B  = 64;    // graphs
constexpr int K  = 10;    // classes
constexpr float NEG = 0.2f;

typedef __attribute__((ext_vector_type(8))) short short8;
typedef __attribute__((ext_vector_type(4))) float floatx4;
typedef __attribute__((ext_vector_type(2))) float floatx2;

DEV float b2f(__hip_bfloat16 x) { return __bfloat162float(x); }
DEV float elu1(float v) { return v > 0.f ? v : (__expf(v) - 1.f); }
DEV unsigned short f2bbits(float f) {
  __hip_bfloat16 b = __float2bfloat16(f);
  return *(unsigned short*)&b;
}
DEV float blo(unsigned u) { return __uint_as_float(u << 16); }
DEV float bhi(unsigned u) { return __uint_as_float(u & 0xffff0000u); }
DEV float bu(unsigned short u) { return __uint_as_float(((unsigned)u) << 16); }
DEV unsigned pack2(float lo, float hi) {
  return (unsigned)f2bbits(lo) | ((unsigned)f2bbits(hi) << 16);
}
// 1/x via v_rcp_f32 + one Newton step (err ~1ulp of f32; output is bf16-rounded)
DEV float rcp_nr(float x) {
  float r = __builtin_amdgcn_rcpf(x);
  return r * (2.f - x * r);
}
// acc(pair of features) += x(pair) * w(broadcast pair held in SGPRs)
DEV void pk_fma(floatx2& acc, floatx2 x, floatx2 w) {
  asm("v_pk_fma_f32 %0, %1, %2, %0" : "+v"(acc) : "v"(x), "s"(w));
}
DEV void pk_add(floatx2& acc, floatx2 w) {
  asm("v_pk_add_f32 %0, %0, %1" : "+v"(acc) : "s"(w));
}

// out1 PERMUTED layout: position p = hp*128 + l16*8 + nt  <->  natural channel
// c = hp*128 + nt*16 + l16  (hp<4, l16<16, nt<8). Dot products over the
// contraction dim are permutation-invariant; W2frag k-rows and b1 are
// permuted to match.

// Self-detection: thread 0 samples 128 even-index bf16 reinterps of x.
DEV int detect_dev(const void* xraw, int* lds) {
  if (threadIdx.x == 0) {
    const __hip_bfloat16* xb = (const __hip_bfloat16*)xraw;
    int bad = 0;
    for (int i = 0; i < 128; ++i) {
      float v = b2f(xb[2 * i]);
      if (!(fabsf(v) < 1e4f)) bad++;
    }
    *lds = (bad < 13) ? 1 : 0;     // 1 = bf16, 0 = f32
  }
  __syncthreads();
  return *lds;
}

#define CVT(p, i) (isbf ? b2f(((const __hip_bfloat16*)(p))[i]) : ((const float*)(p))[i])

// ---------- fused prep ----------
__global__ void fused_prep_kernel(const void* x_raw, const void* w1raw,
                                  const void* as1r, const void* ad1r, const void* b1r,
                                  const void* w2raw,
                                  const void* as2r, const void* ad2r, const void* b2r,
                                  const void* l1wr, const void* l1br,
                                  const void* l2wr, const void* l2br,
                                  unsigned short* __restrict__ xbf,
                                  unsigned short* __restrict__ w1frag,
                                  unsigned short* __restrict__ w2frag,
                                  unsigned short* __restrict__ vfrag,
                                  float* __restrict__ wts,
                                  int* __restrict__ deg,
                                  float* __restrict__ pooled,
                                  int nX, int N) {
  __shared__ int fl;
  int isbf = detect_dev(x_raw, &fl);
  int gid = blockIdx.x * 256 + threadIdx.x;
  int stride = gridDim.x * 256;

  if (isbf) {
    const unsigned short* src = (const unsigned short*)x_raw;
    for (int i = gid; i < nX; i += stride) xbf[i] = src[i];
  } else {
    const float* src = (const float*)x_raw;
    for (int i = gid; i < nX; i += stride) xbf[i] = f2bbits(src[i]);
  }
  // b1 stored PERMUTED: wts[1024 + p] = b1[c_nat(p)]
  for (int i = gid; i < 512;  i += stride) {
    int hp = i >> 7, l16 = (i >> 3) & 15, nt = i & 7;
    int c = hp * 128 + nt * 16 + l16;
    wts[1024 + i] = CVT(b1r, c);
  }
  for (int i = gid; i < 64;   i += stride) wts[1536 + i] = CVT(as2r, i);
  for (int i = gid; i < 64;   i += stride) wts[1600 + i] = CVT(ad2r, i);
  for (int i = gid; i < 64;   i += stride) wts[1664 + i] = CVT(b2r, i);
  for (int i = gid; i < 4096; i += stride) wts[1728 + i] = CVT(l1wr, i);
  for (int i = gid; i < 64;   i += stride) wts[5824 + i] = CVT(l1br, i);
  for (int i = gid; i < 640;  i += stride) wts[5888 + i] = CVT(l2wr, i);
  for (int i = gid; i < 10;   i += stride) wts[6528 + i] = CVT(l2br, i);
  for (int t = gid; t < 8192; t += stride) {
    int lane = t & 63, ks = (t >> 6) & 3, nt = t >> 8;
    for (int j = 0; j < 8; ++j) {
      int k = ks * 32 + (lane >> 4) * 8 + j;
      int n = nt * 16 + (lane & 15);
      w1frag[t * 8 + j] = f2bbits(CVT(w1raw, k * 512 + n));
    }
  }
  // W2frag with PERMUTED k: k index in fragment = position p; fetch W2[c_nat(p)]
  for (int t = gid; t < 4096; t += stride) {
    int lane = t & 63, nt = (t >> 6) & 3, ks = t >> 8;
    for (int j = 0; j < 8; ++j) {
      int p = ks * 32 + (lane >> 4) * 8 + j;          // permuted position
      int hp = p >> 7, pl16 = (p >> 3) & 15, pnt = p & 7;
      int k = hp * 128 + pnt * 16 + pl16;             // natural channel
      int n = nt * 16 + (lane & 15);
      w2frag[t * 8 + j] = f2bbits(CVT(w2raw, k * 64 + n));
    }
  }
  // Vfrag: B-fragment of V[128 x 16], V[:,n<8] = W1[:,n-th head] @ att_src[n],
  // V[:,n>=8] = W1[:, (n-8)-th head] @ att_dst[n-8].  a_s/a_d = x @ V.
  for (int t = gid; t < 2048; t += stride) {
    int j = t & 7, lane = (t >> 3) & 63, ks = t >> 9;
    int k = ks * 32 + (lane >> 4) * 8 + j;
    int n = lane & 15;
    int hh = (n < 8) ? n : (n - 8);
    float s = 0.f;
    if (n < 8) {
      for (int c = 0; c < 64; ++c)
        s += CVT(w1raw, k * 512 + hh * 64 + c) * CVT(as1r, hh * 64 + c);
    } else {
      for (int c = 0; c < 64; ++c)
        s += CVT(w1raw, k * 512 + hh * 64 + c) * CVT(ad1r, hh * 64 + c);
    }
    vfrag[(ks * 64 + lane) * 8 + j] = f2bbits(s);
  }
  for (int i = gid; i < N; i += stride) deg[i] = 0;
  for (int i = gid; i < B * C; i += stride) pooled[i] = 0.f;
}

// ---------- degree count ----------
__global__ void deg_count_kernel(const int* __restrict__ ei, int E, int Etot,
                                 int* __restrict__ deg) {
  int e = blockIdx.x * blockDim.x + threadIdx.x;
  if (e >= Etot) return;
  int d = (e < E) ? ei[E + e] : e - E;
  atomicAdd(&deg[d], 1);
}

// ---------- CSR scans ----------
__global__ void scan_block_kernel(const int* __restrict__ deg,
                                  int* __restrict__ local,
                                  int* __restrict__ bsum, int N) {
  __shared__ int tmp[256];
  int t = threadIdx.x;
  int i = blockIdx.x * 256 + t;
  int v = (i < N) ? deg[i] : 0;
  tmp[t] = v;
  __syncthreads();
  for (int off = 1; off < 256; off <<= 1) {
    int u = (t >= off) ? tmp[t - off] : 0;
    __syncthreads();
    tmp[t] += u;
    __syncthreads();
  }
  if (i < N) local[i] = tmp[t] - v;
  if (t == 255) bsum[blockIdx.x] = tmp[255];
}

__global__ void scan_finish_kernel(const int* __restrict__ local,
                                   const int* __restrict__ bsum, int nb,
                                   int* __restrict__ rowptr,
                                   int* __restrict__ cursor, int N, int Etot) {
  __shared__ int tmp[256];
  __shared__ int offs;
  int t = threadIdx.x;
  int v0 = (t < nb) ? bsum[t] : 0;
  tmp[t] = v0;
  __syncthreads();
  for (int off = 1; off < 256; off <<= 1) {
    int u = (t >= off) ? tmp[t - off] : 0;
    __syncthreads();
    tmp[t] += u;
    __syncthreads();
  }
  if (t == (int)blockIdx.x) offs = tmp[t] - v0;
  __syncthreads();
  int i = blockIdx.x * 256 + t;
  if (i < N) {
    int r = local[i] + offs;
    rowptr[i] = r;
    cursor[i] = r;
  }
  if (i == 0) rowptr[N] = Etot;
}

// ---------- attention scalars: a_s/a_d = x @ V  (4 MFMA per 16 rows) ----------
__global__ __launch_bounds__(256) void att_scalars_kernel(
    const unsigned short* __restrict__ xbf,     // N x 128 bf16
    const unsigned short* __restrict__ vfrag,   // [4ks][64][8] bf16
    float* __restrict__ a_s, float* __restrict__ a_d,   // N x 8
    int N) {
  int t = threadIdx.x, w = t >> 6, lane = t & 63;
  int quad = lane >> 4, l16 = lane & 15;
  int row0 = blockIdx.x * 64 + w * 16;

  floatx4 acc = {};
  int rl = row0 + l16; if (rl >= N) rl = N - 1;
  const unsigned short* xp = xbf + (size_t)rl * 128 + quad * 8;
#pragma unroll
  for (int ks = 0; ks < 4; ++ks) {
    short8 a = *(const short8*)(xp + ks * 32);
    short8 b = *(const short8*)&vfrag[(ks * 64 + lane) * 8];
    acc = __builtin_amdgcn_mfma_f32_16x16x32_bf16(a, b, acc, 0, 0, 0);
  }
  // C layout: col = lane&15 (V column), row = quad*4 + r
#pragma unroll
  for (int r = 0; r < 4; ++r) {
    int row = row0 + quad * 4 + r;
    if (row < N) {
      if (l16 < 8) a_s[(size_t)row * 8 + l16] = acc[r];
      else         a_d[(size_t)row * 8 + (l16 - 8)] = acc[r];
    }
  }
}

// ---------- CSR fill + per-edge softmax weights (f32, CSR slot order) ----------
__global__ void fill_weight_kernel(const int* __restrict__ ei, int E, int Etot,
                                   const float* __restrict__ a_s,
                                   const float* __restrict__ a_d,
                                   int* __restrict__ cursor,
                                   int* __restrict__ col,
                                   float* __restrict__ wedge) {
  int e = blockIdx.x * 256 + threadIdx.x;
  if (e >= Etot) return;
  int s, d;
  if (e < E) { s = ei[e]; d = ei[E + e]; } else { s = d = e - E; }
  int pos = atomicAdd(&cursor[d], 1);
  col[pos] = s;
  float4 s0 = *(const float4*)(a_s + (size_t)s * 8);
  float4 s1 = *(const float4*)(a_s + (size_t)s * 8 + 4);
  float4 d0 = *(const float4*)(a_d + (size_t)d * 8);
  float4 d1 = *(const float4*)(a_d + (size_t)d * 8 + 4);
  float4 w0, w1;
  float v;
  v = s0.x + d0.x; v = v > 0.f ? v : NEG * v; w0.x = __expf(v);
  v = s0.y + d0.y; v = v > 0.f ? v : NEG * v; w0.y = __expf(v);
  v = s0.z + d0.z; v = v > 0.f ? v : NEG * v; w0.z = __expf(v);
  v = s0.w + d0.w; v = v > 0.f ? v : NEG * v; w0.w = __expf(v);
  v = s1.x + d1.x; v = v > 0.f ? v : NEG * v; w1.x = __expf(v);
  v = s1.y + d1.y; v = v > 0.f ? v : NEG * v; w1.y = __expf(v);
  v = s1.z + d1.z; v = v > 0.f ? v : NEG * v; w1.z = __expf(v);
  v = s1.w + d1.w; v = v > 0.f ? v : NEG * v; w1.w = __expf(v);
  *(float4*)(wedge + (size_t)pos * 8)     = w0;
  *(float4*)(wedge + (size_t)pos * 8 + 4) = w1;
}

// ---------- fused x-space aggregation + W1 MFMA + bias/ELU -> out1 ----------
// Block = 512 threads (8 waves) = 8 dests, ONE dest per wave (short serial
// chain). Phase 1: pk_fma accumulation of weighted x rows (feature pairs,
// weight broadcast from SGPRs). Phase 2: all 8 waves split the per-head
// [16x128]@[128x512] GEMM: wave -> (head-pair hp = w>>1, col-half q = w&1).
__global__ __launch_bounds__(512, 8) void aggx_gemm1_kernel(
    const unsigned short* __restrict__ xbf,     // N x 128 bf16
    const unsigned short* __restrict__ W1frag,  // [32][4][64][8] bf16
    const int* __restrict__ rowptr,
    const int* __restrict__ col,
    const float* __restrict__ wedge,            // Etot x 8 f32 (CSR order)
    const float* __restrict__ bias_perm,        // 512, PERMUTED
    unsigned short* __restrict__ out1,          // N x 512 bf16 (PERMUTED)
    int N) {
  // [8 heads][8 dests][128 + 16 pad] bf16 = 18 KB; row stride 288B -> 2-way
  // bank aliasing on phase-2 ds_read_b128 (free).
  __shared__ __align__(16) unsigned short Agg[8 * 8 * 144];
  int t = threadIdx.x, w = t >> 6, lane = t & 63;
  int dbase = blockIdx.x * 8;
  const unsigned* xd = (const unsigned*)xbf;
  unsigned* AggU = (unsigned*)Agg;

  // ---- phase 1: one dest per wave ----
  {
    int d = dbase + w;
    int dd = d < N ? d : N - 1;
    int beg = rowptr[dd], end = rowptr[dd + 1];
    floatx2 acc[8] = {};                  // [head] x {feat0, feat1}
    floatx2 dn01 = {}, dn23 = {}, dn45 = {}, dn67 = {};
#pragma unroll 2
    for (int i = beg; i < end; ++i) {
      int iu = __builtin_amdgcn_readfirstlane(i);
      int s = col[iu];                            // wave-uniform -> s_load
      unsigned xv = xd[((size_t)s << 6) + lane];  // 256B coalesced gather
      const float* wp = wedge + (size_t)iu * 8;   // uniform -> s_load_dwordx8
      float w0 = wp[0], w1 = wp[1], w2 = wp[2], w3 = wp[3];
      float w4 = wp[4], w5 = wp[5], w6 = wp[6], w7 = wp[7];
      floatx2 p01 = {w0, w1}, p23 = {w2, w3}, p45 = {w4, w5}, p67 = {w6, w7};
      pk_add(dn01, p01); pk_add(dn23, p23);
      pk_add(dn45, p45); pk_add(dn67, p67);
      floatx2 xp; xp.x = blo(xv); xp.y = bhi(xv);
      floatx2 b0 = {w0, w0}, b1 = {w1, w1}, b2 = {w2, w2}, b3 = {w3, w3};
      floatx2 b4 = {w4, w4}, b5 = {w5, w5}, b6 = {w6, w6}, b7 = {w7, w7};
      pk_fma(acc[0], xp, b0); pk_fma(acc[1], xp, b1);
      pk_fma(acc[2], xp, b2); pk_fma(acc[3], xp, b3);
      pk_fma(acc[4], xp, b4); pk_fma(acc[5], xp, b5);
      pk_fma(acc[6], xp, b6); pk_fma(acc[7], xp, b7);
    }
    float inv[8];
    inv[0] = rcp_nr(dn01.x + 1e-16f); inv[1] = rcp_nr(dn01.y + 1e-16f);
    inv[2] = rcp_nr(dn23.x + 1e-16f); inv[3] = rcp_nr(dn23.y + 1e-16f);
    inv[4] = rcp_nr(dn45.x + 1e-16f); inv[5] = rcp_nr(dn45.y + 1e-16f);
    inv[6] = rcp_nr(dn67.x + 1e-16f); inv[7] = rcp_nr(dn67.y + 1e-16f);
#pragma unroll
    for (int h = 0; h < 8; ++h)
      AggU[(h * 8 + w) * 72 + lane] =
          pack2(acc[h].x * inv[h], acc[h].y * inv[h]);
  }
  __syncthreads();

  // ---- phase 2: per-head GEMM from LDS, bias + ELU, permuted store ----
  {
    int quad = lane >> 4, l16 = lane & 15;
    int hp = w >> 1, q = w & 1;
    int h = hp * 2 + q;                   // cols nt = q*4..q*4+3 belong to head h
    floatx4 acc2[4] = {};
    const unsigned short* Bp = W1frag + (size_t)hp * 16384;
#pragma unroll
    for (int ks = 0; ks < 4; ++ks) {
      short8 a = *(const short8*)&Agg[(h * 8 + (l16 & 7)) * 144 + ks * 32 + quad * 8];
#pragma unroll
      for (int j = 0; j < 4; ++j) {
        int nt = q * 4 + j;
        short8 b = *(const short8*)&Bp[((nt * 4 + ks) * 64 + lane) * 8];
        acc2[j] = __builtin_amdgcn_mfma_f32_16x16x32_bf16(a, b, acc2[j], 0, 0, 0);
      }
    }
    float4 bq = *(const float4*)&bias_perm[hp * 128 + l16 * 8 + q * 4];
#pragma unroll
    for (int r = 0; r < 4; ++r) {
      int dl = quad * 4 + r;              // C row; valid dests are rows 0..7
      int row = dbase + dl;
      if (dl < 8 && row < N) {
        uint2 o;
        o.x = pack2(elu1(acc2[0][r] + bq.x), elu1(acc2[1][r] + bq.y));
        o.y = pack2(elu1(acc2[2][r] + bq.z), elu1(acc2[3][r] + bq.w));
        *(uint2*)&out1[(size_t)row * 512 + hp * 128 + l16 * 8 + q * 4] = o;
      }
    }
  }
}

// ---------- layer 2: MFMA bf16 GEMM (k-dim permuted to match out1bf) ----------
__global__ __launch_bounds__(256) void gemm2_mfma_kernel(
    const unsigned short* __restrict__ x2bf,    // N x 512 bf16 (PERMUTED k)
    const unsigned short* __restrict__ W2frag,  // [16ks][4nt][64][8] bf16 (perm k)
    const float* __restrict__ att_src,          // 64
    const float* __restrict__ att_dst,
    unsigned short* __restrict__ h2,            // N x 64 bf16 (natural)
    float* __restrict__ a_s, float* __restrict__ a_d,  // N
    int N) {
  int t = threadIdx.x;
  int w = t >> 6, lane = t & 63;
  int quad = lane >> 4, l16 = lane & 15;
  int rowbase = blockIdx.x * 64 + w * 16;

  floatx4 acc[4] = {};
  int r0 = rowbase + l16; if (r0 >= N) r0 = N - 1;
  const unsigned short* p0 = x2bf + (size_t)r0 * 512 + quad * 8;
#pragma unroll
  for (int ks = 0; ks < 16; ++ks) {
    short8 a0 = *(const short8*)(p0 + ks * 32);
#pragma unroll
    for (int nt = 0; nt < 4; ++nt) {
      short8 b = *(const short8*)&W2frag[((ks * 4 + nt) * 64 + lane) * 8];
      acc[nt] = __builtin_amdgcn_mfma_f32_16x16x32_bf16(a0, b, acc[nt], 0, 0, 0);
    }
  }

  float asw[4], adw[4];
#pragma unroll
  for (int nt = 0; nt < 4; ++nt) {
    asw[nt] = att_src[nt * 16 + l16];
    adw[nt] = att_dst[nt * 16 + l16];
  }
  float ps[4] = {}, pd[4] = {};
#pragma unroll
  for (int nt = 0; nt < 4; ++nt)
#pragma unroll
    for (int r = 0; r < 4; ++r) {
      float v = acc[nt][r];
      int row = rowbase + quad * 4 + r;
      if (row < N) h2[(size_t)row * 64 + nt * 16 + l16] = f2bbits(v);
      ps[r] += v * asw[nt];
      pd[r] += v * adw[nt];
    }
#pragma unroll
  for (int r = 0; r < 4; ++r) {
    float p = ps[r], q = pd[r];
#pragma unroll
    for (int off = 1; off < 16; off <<= 1) {
      p += __shfl_xor(p, off);
      q += __shfl_xor(q, off);
    }
    int row = rowbase + quad * 4 + r;
    if (l16 == 0 && row < N) {
      a_s[row] = p;
      a_d[row] = q;
    }
  }
}

// H=1, quarter-wave edge grouping (h2 natural layout).
__global__ void gat_agg1_kernel(const int* __restrict__ rowptr,
                                const int* __restrict__ col,
                                const float* __restrict__ a_s,
                                const float* __restrict__ a_d,
                                const unsigned short* __restrict__ hfeat,
                                const float* __restrict__ bias,
                                unsigned short* __restrict__ out, int N) {
  int wave = threadIdx.x >> 6, lane = threadIdx.x & 63;
  int d = blockIdx.x * 4 + wave;
  if (d >= N) return;
  int beg = rowptr[d], end = rowptr[d + 1];
  int qg = lane >> 4, l16 = lane & 15;
  float adv = a_d[d];
  const uint2* hfu = (const uint2*)hfeat;
  float acc[4] = {};
  float wsum = 0.f;
#pragma unroll 2
  for (int i = beg + qg; i < end; i += 4) {
    int s = col[i];
    float v = a_s[s] + adv;
    v = v > 0.f ? v : NEG * v;
    float wv = __expf(v);
    wsum += wv;
    uint2 u = hfu[(size_t)s * 16 + l16];
    acc[0] += wv * blo(u.x); acc[1] += wv * bhi(u.x);
    acc[2] += wv * blo(u.y); acc[3] += wv * bhi(u.y);
  }
#pragma unroll
  for (int off = 16; off <= 32; off <<= 1) {
#pragma unroll
    for (int j = 0; j < 4; ++j) acc[j] += __shfl_xor(acc[j], off);
    wsum += __shfl_xor(wsum, off);
  }
  float winv = 1.f / (wsum + 1e-16f);
  float4 bb = ((const float4*)bias)[l16];
  float r0 = elu1(acc[0] * winv + bb.x), r1 = elu1(acc[1] * winv + bb.y);
  float r2 = elu1(acc[2] * winv + bb.z), r3 = elu1(acc[3] * winv + bb.w);
  if (qg == 0) {
    uint2 o; o.x = pack2(r0, r1); o.y = pack2(r2, r3);
    ((uint2*)out)[(size_t)d * 16 + l16] = o;
  }
}

// ---------- pooling: 16 nodes per wave ----------
__global__ void pool_kernel(const unsigned short* __restrict__ out2,
                            const int* __restrict__ batch,
                            float* __restrict__ pooled, int N) {
  int wave = threadIdx.x >> 6, lane = threadIdx.x & 63;
  int seg = blockIdx.x * 4 + wave;
  int start = seg * 16;
  if (start >= N) return;
  int end = min(start + 16, N);
  int cur = batch[start];
  float acc = 0.f;
  for (int n = start; n < end; ++n) {
    int bn = batch[n];
    if (bn != cur) {
      unsafeAtomicAdd(&pooled[cur * 64 + lane], acc);
      acc = 0.f; cur = bn;
    }
    acc += bu(out2[(size_t)n * 64 + lane]);
  }
  unsafeAtomicAdd(&pooled[cur * 64 + lane], acc);
}

// ---------- MLP head + log_softmax: one block (one wave) per graph ----------
__global__ void head_kernel(const float* __restrict__ pooled,
                            const float* __restrict__ lin1_w,
                            const float* __restrict__ lin1_b,
                            const float* __restrict__ lin2_w,
                            const float* __restrict__ lin2_b,
                            const void* __restrict__ x_raw,
                            void* __restrict__ outv) {
  __shared__ float P[C];
  __shared__ float Zs[C];
  __shared__ float Ls[K];
  __shared__ float lse_s;
  __shared__ int fl;
  int isbf = detect_dev(x_raw, &fl);
  int g = blockIdx.x, t = threadIdx.x;   // 64 threads
  P[t] = pooled[g * C + t];
  __syncthreads();
  float acc = lin1_b[t];
  for (int k = 0; k < C; ++k) acc += P[k] * lin1_w[k * C + t];
  Zs[t] = elu1(acc);
  __syncthreads();
  if (t < K) {
    float a = lin2_b[t];
    for (int k = 0; k < C; ++k) a += Zs[k] * lin2_w[k * K + t];
    Ls[t] = a;
  }
  __syncthreads();
  if (t == 0) {
    float mx = -1e30f;
    for (int c = 0; c < K; ++c) mx = fmaxf(mx, Ls[c]);
    float s = 0.f;
    for (int c = 0; c < K; ++c) s += __expf(Ls[c] - mx);
    lse_s = mx + __logf(s);
  }
  __syncthreads();
  if (t < K) {
    float val = Ls[t] - lse_s;
    if (isbf) ((__hip_bfloat16*)outv)[g * K + t] = __float2bfloat16(val);
    else      ((float*)outv)[g * K + t] = val;
  }
}

extern "C" void kernel_launch(void* const* d_in, const int* in_sizes, int n_in,
                              void* d_out, int out_size, void* d_ws, size_t ws_size,
                              hipStream_t stream) {
  const void* x_raw = d_in[0];
  const int*  ei    = (const int*)d_in[1];
  const int*  batch = (const int*)d_in[2];

  const int N    = in_sizes[2];
  const int E    = in_sizes[1] / 2;
  const int Etot = E + N;
  const int nb   = (N + 255) / 256;

  float* ws   = (float*)d_ws;
  size_t off  = 0;

  float* wts = ws + off; off += 6544;
  float* b1w  = wts + 1024;
  float* as2w = wts + 1536;
  float* ad2w = wts + 1600;
  float* b2w  = wts + 1664;
  float* l1w  = wts + 1728;
  float* l1b  = wts + 5824;
  float* l2w  = wts + 5888;
  float* l2b  = wts + 6528;

  unsigned short* xbf    = (unsigned short*)(ws + off); off += (size_t)N * 64;
  unsigned short* w1frag = (unsigned short*)(ws + off); off += 32768;
  unsigned short* w2frag = (unsigned short*)(ws + off); off += 16384;
  unsigned short* vfrag  = (unsigned short*)(ws + off); off += 1024;
  float* wedge           = ws + off;                    off += (size_t)Etot * 8;
  unsigned short* out1bf = (unsigned short*)(ws + off); off += (size_t)N * 256;
  unsigned short* h2bf   = (unsigned short*)(ws + off); off += (size_t)N * 32;
  unsigned short* out2bf = (unsigned short*)(ws + off); off += (size_t)N * 32;
  float* as1  = ws + off; off += (size_t)N * H1;
  float* ad1  = ws + off; off += (size_t)N * H1;
  float* as2  = ws + off; off += (size_t)N;
  float* ad2  = ws + off; off += (size_t)N;
  float* pooled = ws + off; off += (size_t)B * C;

  int* ibase  = (int*)(ws + off);
  int* deg    = ibase;                 ibase += N;
  int* cursor = ibase;                 ibase += N;
  int* rowptr = ibase;                 ibase += N + 1;
  int* locals = ibase;                 ibase += N;
  int* bsum   = ibase;                 ibase += 256;
  int* col    = ibase;                 ibase += Etot;

  // ---- prep ----
  fused_prep_kernel<<<1024, 256, 0, stream>>>(
      x_raw, d_in[3], d_in[4], d_in[5], d_in[6], d_in[7], d_in[8], d_in[9],
      d_in[10], d_in[11], d_in[12], d_in[13], d_in[14],
      xbf, w1frag, w2frag, vfrag, wts, deg, pooled, in_sizes[0], N);

  // ---- CSR: deg + scans ----
  deg_count_kernel<<<(Etot + 255) / 256, 256, 0, stream>>>(ei, E, Etot, deg);
  scan_block_kernel<<<nb, 256, 0, stream>>>(deg, locals, bsum, N);
  scan_finish_kernel<<<nb, 256, 0, stream>>>(locals, bsum, nb, rowptr, cursor, N, Etot);

  // ---- layer-1 attention scalars via factored V (tiny MFMA GEMM) ----
  att_scalars_kernel<<<(N + 63) / 64, 256, 0, stream>>>(xbf, vfrag, as1, ad1, N);

  // ---- CSR fill + per-edge softmax weights ----
  fill_weight_kernel<<<(Etot + 255) / 256, 256, 0, stream>>>(
      ei, E, Etot, as1, ad1, cursor, col, wedge);

  // ---- fused x-space aggregation + W1 GEMM -> out1 ----
  aggx_gemm1_kernel<<<(N + 7) / 8, 512, 0, stream>>>(
      xbf, w1frag, rowptr, col, wedge, b1w, out1bf, N);

  // ---- layer 2 ----
  gemm2_mfma_kernel<<<(N + 63) / 64, 256, 0, stream>>>(out1bf, w2frag, as2w, ad2w,
                                                       h2bf, as2, ad2, N);
  gat_agg1_kernel<<<(N + 3) / 4, 256, 0, stream>>>(rowptr, col, as2, ad2, h2bf, b2w, out2bf, N);

  // ---- pool + head ----
  pool_kernel<<<(N + 63) / 64, 256, 0, stream>>>(out2bf, batch, pooled, N);
  head_kernel<<<B, 64, 0, stream>>>(pooled, l1w, l1b, l2w, l2b, x_raw, (void*)d_out);
}